// Round 3
// baseline (152.439 us; speedup 1.0000x reference)
//
#include <hip/hip_runtime.h>
#include <hip/hip_bf16.h>
#include <math.h>

#define N_SPECIES 4
#define NNZ       16384
#define MPS       4096      // NNZ / N_SPECIES
#define N_CELLS   512
#define N_LATENT  256
#define HDIM      1024
#define N_GENES   20000

#define STRIPE    32
#define NSTRIPE   (N_GENES / STRIPE)        // 625
#define NBUCKET   (N_SPECIES * NSTRIPE)     // 2500
#define CAP       64
#define KCHUNK    128

typedef __bf16 bf16x8 __attribute__((ext_vector_type(8)));
typedef float  f32x4  __attribute__((ext_vector_type(4)));

static __device__ __forceinline__ unsigned short f2b(float f) {
    __hip_bfloat16 h = __float2bfloat16(f);
    return __builtin_bit_cast(unsigned short, h);
}
static __device__ __forceinline__ float softplusf(float x) {
    return (x > 20.f) ? x : log1pf(expf(x));
}

// ---------------------------------------------------------------------------
// Kernel 1: transpose + convert W (S, K, N) f32  ->  Wt (S, N, K) bf16
// (used for W1, W2 — small)
// ---------------------------------------------------------------------------
__global__ __launch_bounds__(256) void transpose_bf16(
    const float* __restrict__ W, unsigned short* __restrict__ Wt, int K, int N)
{
    __shared__ float tile[32][33];
    int s = blockIdx.z;
    const float* Ws = W + (size_t)s * K * N;
    unsigned short* Wts = Wt + (size_t)s * N * K;
    int n0 = blockIdx.x * 32, k0 = blockIdx.y * 32;
    int tx = threadIdx.x, ty = threadIdx.y;   // block (32, 8)
    #pragma unroll
    for (int p = 0; p < 4; p++)
        tile[ty + 8 * p][tx] = Ws[(size_t)(k0 + ty + 8 * p) * N + n0 + tx];
    __syncthreads();
    #pragma unroll
    for (int p = 0; p < 4; p++) {
        int r = ty + 8 * p;
        Wts[(size_t)(n0 + r) * K + k0 + tx] = f2b(tile[tx][r]);
    }
}

// ---------------------------------------------------------------------------
// Kernel 2: build combined input  A (S, 512, 512) bf16
// ---------------------------------------------------------------------------
__global__ __launch_bounds__(256) void build_combined(
    const float* __restrict__ z, const float* __restrict__ gl,
    const int* __restrict__ bidx, unsigned short* __restrict__ A)
{
    int idx = blockIdx.x * 256 + threadIdx.x;
    int c = idx & 511;
    int r = (idx >> 9) & 511;
    int s = idx >> 18;
    float v;
    if (c < N_LATENT)
        v = z[((size_t)s * MPS + r) * N_LATENT + c];
    else
        v = gl[(size_t)bidx[s * MPS + r] * N_LATENT + (c - N_LATENT)];
    A[idx] = f2b(v);
}

// ---------------------------------------------------------------------------
// Kernel 3: bf16 MFMA GEMM:  C = relu(A @ B + bias)
//   A (S,M,K) bf16 row-major, Bt (S,N,K) bf16 n-major
// Tile BM=BN=64, BK=64, 4 waves (2x2), wave = 32x32, XOR-swizzled LDS
// ---------------------------------------------------------------------------
__global__ __launch_bounds__(256) void gemm_bf16_mfma(
    const unsigned short* __restrict__ A, const unsigned short* __restrict__ Bt,
    const float* __restrict__ bias, void* __restrict__ Cptr,
    int M, int N, int K, int out_bf16)
{
    int s = blockIdx.z;
    const unsigned short* As = A  + (size_t)s * M * K;
    const unsigned short* Bs = Bt + (size_t)s * N * K;
    const float* bvec = bias + (size_t)s * N;

    int m0 = blockIdx.x * 64, n0 = blockIdx.y * 64;

    __shared__ unsigned short Alds[64 * 64];
    __shared__ unsigned short Blds[64 * 64];

    int tid  = threadIdx.x;
    int lane = tid & 63, w = tid >> 6;
    int wr = w >> 1, wc = w & 1;

    f32x4 acc[2][2] = {};

    for (int kt = 0; kt < K; kt += 64) {
        #pragma unroll
        for (int it = 0; it < 2; it++) {
            int c   = it * 256 + tid;
            int row = c >> 3, kb = c & 7;
            int pa  = kb ^ (row & 7);
            uint4 va = *(const uint4*)(As + (size_t)(m0 + row) * K + kt + kb * 8);
            *(uint4*)(Alds + row * 64 + pa * 8) = va;
            uint4 vb = *(const uint4*)(Bs + (size_t)(n0 + row) * K + kt + kb * 8);
            *(uint4*)(Blds + row * 64 + pa * 8) = vb;
        }
        __syncthreads();
        #pragma unroll
        for (int ks = 0; ks < 2; ks++) {
            bf16x8 af[2], bfr[2];
            #pragma unroll
            for (int f = 0; f < 2; f++) {
                int ar  = wr * 32 + f * 16 + (lane & 15);
                int akb = (ks * 4 + (lane >> 4)) ^ (ar & 7);
                af[f]  = __builtin_bit_cast(bf16x8, *(const uint4*)(Alds + ar * 64 + akb * 8));
                int br  = wc * 32 + f * 16 + (lane & 15);
                int bkb = (ks * 4 + (lane >> 4)) ^ (br & 7);
                bfr[f] = __builtin_bit_cast(bf16x8, *(const uint4*)(Blds + br * 64 + bkb * 8));
            }
            #pragma unroll
            for (int fm = 0; fm < 2; fm++)
                #pragma unroll
                for (int fn = 0; fn < 2; fn++)
                    acc[fm][fn] = __builtin_amdgcn_mfma_f32_16x16x32_bf16(
                        af[fm], bfr[fn], acc[fm][fn], 0, 0, 0);
        }
        __syncthreads();
    }

    #pragma unroll
    for (int fm = 0; fm < 2; fm++)
        #pragma unroll
        for (int fn = 0; fn < 2; fn++) {
            int col = n0 + wc * 32 + fn * 16 + (lane & 15);
            float bv = bvec[col];
            #pragma unroll
            for (int r = 0; r < 4; r++) {
                int row = m0 + wr * 32 + fm * 16 + (lane >> 4) * 4 + r;
                float v = acc[fm][fn][r] + bv;
                v = fmaxf(v, 0.0f);
                size_t off = (size_t)s * M * N + (size_t)row * N + col;
                if (out_bf16) ((unsigned short*)Cptr)[off] = f2b(v);
                else          ((float*)Cptr)[off] = v;
            }
        }
}

// ---------------------------------------------------------------------------
// Kernel 4a: zero the bucket counters (+ overflow counter)
// ---------------------------------------------------------------------------
__global__ __launch_bounds__(256) void zero_aux(int* __restrict__ counts)
{
    int i = blockIdx.x * 256 + threadIdx.x;
    if (i <= NBUCKET) counts[i] = 0;     // [NBUCKET] = overflow counter
}

// ---------------------------------------------------------------------------
// Kernel 4b: bucket entries by (species, 32-gene stripe)
// ---------------------------------------------------------------------------
__global__ __launch_bounds__(256) void bucket_entries(
    const int* __restrict__ gidx, int* __restrict__ counts,
    int* __restrict__ lists, int* __restrict__ ovf_list)
{
    int j = blockIdx.x * 256 + threadIdx.x;      // 0..NNZ-1
    int s = j >> 12;
    int sb = s * NSTRIPE + (gidx[j] >> 5);
    int pos = atomicAdd(&counts[sb], 1);
    if (pos < CAP) lists[sb * CAP + pos] = j;
    else           ovf_list[atomicAdd(&counts[NBUCKET], 1)] = j;
}

// ---------------------------------------------------------------------------
// Kernel 5: fused stripe decode — stream W3 panel once, coalesced.
// One block per (species, stripe). LDS chunk [128][33] f32 (pad -> 2-way max).
// Wave w handles list entries w, w+4, w+8, ... (up to CAP=64 -> acc[8]/lane..
// wait: 16 per wave max; acc[16]).
// ---------------------------------------------------------------------------
__global__ __launch_bounds__(256) void decode_stripe(
    const float* __restrict__ H2, const int* __restrict__ bidx,
    const int* __restrict__ gidx, const float* __restrict__ W3,
    const float* __restrict__ b3, const int* __restrict__ counts,
    const int* __restrict__ lists, float* __restrict__ out)
{
    __shared__ float tile[KCHUNK][STRIPE + 1];
    int sb = blockIdx.x;
    int s  = sb / NSTRIPE;
    int g0 = (sb % NSTRIPE) * STRIPE;
    int cnt = counts[sb];
    cnt = (cnt < CAP) ? cnt : CAP;
    if (cnt == 0) return;

    const float* Ws = W3 + (size_t)s * HDIM * N_GENES;
    int tid = threadIdx.x, lane = tid & 63, w = tid >> 6;

    for (int base = 0; base < cnt; base += 32) {
        // hoist this pass's entry metadata (8 entries per wave)
        int jj[8], bb[8], gg[8];
        #pragma unroll
        for (int e = 0; e < 8; e++) {
            int li = base + e * 4 + w;
            if (li < cnt) {
                jj[e] = lists[sb * CAP + li];
                bb[e] = bidx[jj[e]];
                gg[e] = gidx[jj[e]] - g0;
            } else jj[e] = -1;
        }
        float acc[8] = {};

        for (int kc = 0; kc < HDIM; kc += KCHUNK) {
            // stage 128 x 32 f32 panel (coalesced float4 loads)
            {
                int r = tid >> 3, c = (tid & 7) * 4;
                #pragma unroll
                for (int p = 0; p < KCHUNK / 32; p++) {
                    int kl = r + p * 32;
                    float4 v = *(const float4*)(Ws + (size_t)(kc + kl) * N_GENES + g0 + c);
                    tile[kl][c] = v.x; tile[kl][c + 1] = v.y;
                    tile[kl][c + 2] = v.z; tile[kl][c + 3] = v.w;
                }
            }
            __syncthreads();
            #pragma unroll
            for (int e = 0; e < 8; e++) {
                if (jj[e] >= 0) {
                    const float* h = H2 + ((size_t)s * N_CELLS + bb[e]) * HDIM + kc;
                    acc[e] += h[lane]      * tile[lane][gg[e]]
                            + h[lane + 64] * tile[lane + 64][gg[e]];
                }
            }
            __syncthreads();
        }

        #pragma unroll
        for (int e = 0; e < 8; e++) {
            float sum = acc[e];
            #pragma unroll
            for (int off = 32; off; off >>= 1)
                sum += __shfl_xor(sum, off, 64);
            if (jj[e] >= 0 && lane == 0)
                out[jj[e]] = softplusf(sum + b3[(size_t)s * N_GENES + gg[e] + g0]);
        }
    }
}

// ---------------------------------------------------------------------------
// Kernel 6: overflow fallback (strided column dot) — statistically never runs
// ---------------------------------------------------------------------------
__global__ __launch_bounds__(256) void decode_overflow(
    const float* __restrict__ H2, const int* __restrict__ bidx,
    const int* __restrict__ gidx, const float* __restrict__ W3,
    const float* __restrict__ b3, const int* __restrict__ counts,
    const int* __restrict__ ovf_list, float* __restrict__ out)
{
    int n = counts[NBUCKET] - NBUCKET * 0;       // overflow count
    n = counts[NBUCKET];
    int lane = threadIdx.x & 63;
    for (int i = blockIdx.x * 4 + (threadIdx.x >> 6); i < n; i += gridDim.x * 4) {
        int j = ovf_list[i];
        int s = j >> 12;
        int bi = bidx[j], gi = gidx[j];
        const float* h    = H2 + ((size_t)s * N_CELLS + bi) * HDIM;
        const float* wcol = W3 + (size_t)s * HDIM * N_GENES + gi;
        float sum = 0.f;
        #pragma unroll
        for (int t = 0; t < HDIM / 64; t++) {
            int k = t * 64 + lane;
            sum += h[k] * wcol[(size_t)k * N_GENES];
        }
        #pragma unroll
        for (int off = 32; off; off >>= 1)
            sum += __shfl_xor(sum, off, 64);
        if (lane == 0)
            out[j] = softplusf(sum + b3[(size_t)s * N_GENES + gi]);
    }
}

// ---------------------------------------------------------------------------
extern "C" void kernel_launch(void* const* d_in, const int* in_sizes, int n_in,
                              void* d_out, int out_size, void* d_ws, size_t ws_size,
                              hipStream_t stream) {
    const int*   batch_idx = (const int*)  d_in[1];
    const int*   gene_idx  = (const int*)  d_in[2];
    const float* gl        = (const float*)d_in[3];
    const float* z         = (const float*)d_in[4];
    const float* W1        = (const float*)d_in[5];
    const float* b1        = (const float*)d_in[6];
    const float* W2        = (const float*)d_in[7];
    const float* b2        = (const float*)d_in[8];
    const float* W3        = (const float*)d_in[9];
    const float* b3        = (const float*)d_in[10];
    float* out = (float*)d_out;

    char* ws = (char*)d_ws;
    unsigned short* Wt1  = (unsigned short*)(ws + 0);                 //  4 MB (4,1024,512)  bf16
    unsigned short* Wt2  = (unsigned short*)(ws + (4ull  << 20));     //  8 MB (4,1024,1024) bf16
    unsigned short* Acmb = (unsigned short*)(ws + (12ull << 20));     //  2 MB (4,512,512)   bf16
    unsigned short* H1   = (unsigned short*)(ws + (14ull << 20));     //  4 MB (4,512,1024)  bf16
    float*          H2   = (float*)        (ws + (18ull << 20));      //  8 MB (4,512,1024)  f32
    int*            counts   = (int*)      (ws + (26ull << 20));      // NBUCKET+1 ints
    int*            lists    = (int*)      (ws + (27ull << 20));      // NBUCKET*CAP ints (640KB)
    int*            ovf_list = (int*)      (ws + (28ull << 20));      // NNZ ints

    // --- bucket entries by (species, gene stripe)
    zero_aux<<<(NBUCKET + 256) / 256, 256, 0, stream>>>(counts);
    bucket_entries<<<NNZ / 256, 256, 0, stream>>>(gene_idx, counts, lists, ovf_list);

    // --- weight transposes (f32 -> bf16, n-major) for the MLP
    transpose_bf16<<<dim3(HDIM / 32, (2 * N_LATENT) / 32, N_SPECIES), dim3(32, 8), 0, stream>>>(
        W1, Wt1, 2 * N_LATENT, HDIM);
    transpose_bf16<<<dim3(HDIM / 32, HDIM / 32, N_SPECIES), dim3(32, 8), 0, stream>>>(
        W2, Wt2, HDIM, HDIM);

    // --- combined input (concat z rows with gathered global latent)
    build_combined<<<(N_SPECIES * N_CELLS * 2 * N_LATENT) / 256, 256, 0, stream>>>(
        z, gl, batch_idx, Acmb);

    // --- layer 1: H1 = relu(Acmb @ W1 + b1)   M=512 K=512 N=1024, bf16 out
    gemm_bf16_mfma<<<dim3(N_CELLS / 64, HDIM / 64, N_SPECIES), 256, 0, stream>>>(
        Acmb, Wt1, b1, H1, N_CELLS, HDIM, 2 * N_LATENT, 1);

    // --- layer 2: H2 = relu(H1 @ W2 + b2)     M=512 K=1024 N=1024, f32 out
    gemm_bf16_mfma<<<dim3(N_CELLS / 64, HDIM / 64, N_SPECIES), 256, 0, stream>>>(
        H1, Wt2, b2, H2, N_CELLS, HDIM, HDIM, 0);

    // --- fused decode: stream W3 once, coalesced, via stripe buckets
    decode_stripe<<<NBUCKET, 256, 0, stream>>>(
        H2, batch_idx, gene_idx, W3, b3, counts, lists, out);
    decode_overflow<<<32, 256, 0, stream>>>(
        H2, batch_idx, gene_idx, W3, b3, counts, ovf_list, out);
}